// Round 3
// baseline (3326.106 us; speedup 1.0000x reference)
//
#include <hip/hip_runtime.h>
#include <stdint.h>

// VectorQuantization: out[n] = codebook[argmax_k dot(x[n], codebook[k])]
// (L2-normalize is a positive row-scalar -> argmax-invariant -> skipped)
//
// R6: true m201-style pipelined phase schedule. R4/R5 read fragments in the
// same phase that consumed them -> ds_read burst serialized in front of each
// MFMA cluster (pipes serialized; MfmaUtil 34-38%). Now each K-tile is 2
// phases of 16 MFMA with fragment reads issued ONE PHASE AHEAD into an
// alternate register set (A0/A1 per-K-tile, B0/B1 per-phase), 2 raw
// s_barriers per phase, setprio(1) around clusters. The compiler's counted
// lgkmcnt before each cluster then waits only on reads that have had a full
// 16-MFMA window (~310 SIMD-cyc) to land.
//
// Phase layout per kt (buffer bk=kt&3):
//   phase A: issue B1 <- bk.B[4..7] (4 ds_read); stage kt+3 (4 gll);
//            barrier; [lgkm] 16 MFMA j=0..3 (A_cur,B0); barrier.
//   phase B: counted vmcnt (gates buf kt+1 landed); issue A_nxt <- (kt+1).A,
//            B0 <- (kt+1).B[0..3] (8 ds_read); barrier; [lgkm] 16 MFMA
//            j=4..7 (A_cur,B1) [+ fold(0..3) interleaved at kt%16==15];
//            fold(4..7) after; barrier.
//
// Race ledger: stages issued in phase A of kt target buf (kt+3)&3=(kt-1)&3.
// Last reads of buf kt-1: B[4..7] issued phase A of kt-1, completed before
// phase B of kt-1's MFMA (compiler lgkm) -> >=2 barriers before kt's stage
// issue. Reads of buf kt+1 (phase B of kt) are gated by vmcnt(8): at that
// point outstanding stages = {kt+1,kt+2,kt+3} = 12/wave -> wait 8 leaves
// kt+1's 4 landed. Tail: vmcnt(4) at G-3, vmcnt(0) at G-2, no reads at G-1.
// Prologue stages kt 0,1,2 (12), vmcnt(8), barrier, pre-reads kt0 frags.
//
// Carried: zero-bank-conflict XOR chunk swizzle (SQ_LDS_BANK_CONFLICT == 0),
// packed-key top-2 epilogue (+4.0 bias -> u32-monotone, 6-bit inverted
// (tile,j) code in low mantissa, <=64 ulp << MARGIN), ballot winner-lane
// recovery, exact-fp64 recheck within MARGIN, fused to_f16.

typedef _Float16 half8 __attribute__((ext_vector_type(8)));
typedef _Float16 half4v __attribute__((ext_vector_type(4)));
typedef float f32x4 __attribute__((ext_vector_type(4)));

#define M_ROWS 8192
#define DIM 512
#define K_CODES 16384
#define BM 256
#define BN 256
#define BK 32
#define NSPLIT 16
#define NT ((K_CODES / NSPLIT) / BN) /* 4 col-tiles per block */
#define KT_CT (DIM / BK)             /* 16 K-tiles per col-tile */
#define G (NT * KT_CT)               /* 64 K-tiles per block */
#define MARGIN 2.0e-3f
#define BIAS 4.0f

typedef __attribute__((address_space(1))) uint32_t as1_u32;
typedef __attribute__((address_space(3))) uint32_t as3_u32;

__device__ __forceinline__ void gll16(const void* g, void* l) {
  // async global->LDS, 16B/lane; LDS dest = wave-uniform base + lane*16
  __builtin_amdgcn_global_load_lds((const as1_u32*)(uintptr_t)g,
                                   (as3_u32*)(uintptr_t)l, 16, 0, 0);
}

__global__ void to_f16_all(const float* __restrict__ x, const float* __restrict__ cb,
                           _Float16* __restrict__ xh, _Float16* __restrict__ ch) {
  const int NX = M_ROWS * DIM / 4;
  int i = blockIdx.x * 256 + threadIdx.x;
  float4 v;
  if (i < NX) v = reinterpret_cast<const float4*>(x)[i];
  else        v = reinterpret_cast<const float4*>(cb)[i - NX];
  half4v h = {(_Float16)v.x, (_Float16)v.y, (_Float16)v.z, (_Float16)v.w};
  if (i < NX) reinterpret_cast<half4v*>(xh)[i] = h;
  else        reinterpret_cast<half4v*>(ch)[i - NX] = h;
}

__global__ __launch_bounds__(512, 2) void vq_argmax(
    const _Float16* __restrict__ xh, const _Float16* __restrict__ ch,
    float* __restrict__ pv, int* __restrict__ pi) {
  // 4 rotating single-K-tile buffers x {A,B} x (256 rows x 32 k) = 128 KiB
  __shared__ _Float16 lds[4][2][BM * BK];

  const int tid = threadIdx.x;
  const int lane = tid & 63;
  const int w = tid >> 6;
  const int wm = w >> 1, wn = w & 1;       // 4M x 2N wave grid
  const int l15 = lane & 15, quad = lane >> 4;
  const int row0 = blockIdx.x * BM;
  const int split = blockIdx.y;
  // swizzled k-chunk element offset for this lane's fragment reads
  const int kq = ((quad ^ ((l15 >> 1) & 3)) << 3);
  const int aoff = (wm * 64 + l15) * BK + kq;
  const int boff = (wn * 128 + l15) * BK + kq;

  // staging: slot s = r*512+tid holds logical chunk (row=s>>2, kc=(s&3)^((row>>1)&3))
  int eoff0, eoff1, doff0, doff1;
  {
    const int s1 = 512 + tid;
    const int r0 = tid >> 2, r1 = s1 >> 2;
    eoff0 = r0 * DIM + ((((tid & 3) ^ ((r0 >> 1) & 3))) << 3);
    eoff1 = r1 * DIM + ((((s1 & 3) ^ ((r1 >> 1) & 3))) << 3);
    doff0 = (tid & 448) << 3;
    doff1 = (512 + (tid & 448)) << 3;
  }
  const _Float16* Asrc = xh + (size_t)row0 * DIM;
  const _Float16* Bsrc = ch + (size_t)split * (K_CODES / NSPLIT) * DIM;

  auto stageA = [&](int t) {
    const int b = t & 3, ko = (t & 15) * BK;
    const _Float16* g = Asrc + ko;
    _Float16* l = &lds[b][0][0];
    gll16(g + eoff0, l + doff0);
    gll16(g + eoff1, l + doff1);
  };
  auto stageB = [&](int t) {
    const int b = t & 3, ko = (t & 15) * BK;
    const _Float16* g = Bsrc + (size_t)(t >> 4) * (BN * DIM) + ko;
    _Float16* l = &lds[b][1][0];
    gll16(g + eoff0, l + doff0);
    gll16(g + eoff1, l + doff1);
  };

  // packed top-2 keys per (i,r) row-slot: high bits = biased-sim f32 bits,
  // low 6 bits = inverted (coltile,j) code (bigger key = better / lower idx)
  unsigned K1[4][4], K2[4][4];
#pragma unroll
  for (int i = 0; i < 4; ++i)
#pragma unroll
    for (int r = 0; r < 4; ++r) { K1[i][r] = 0u; K2[i][r] = 0u; }

  f32x4 acc[4][8];
  half8 A0[4], A1[4], B0[4], B1[4];

  auto fold = [&](int j0, int j1, int kt) {
    const unsigned icb = 63u - (unsigned)(kt >> 4) * 8u;  // icode = icb - j
#pragma unroll
    for (int j = j0; j < j1; ++j) {
      const unsigned xo = 63u ^ (icb - (unsigned)j);
#pragma unroll
      for (int i = 0; i < 4; ++i)
#pragma unroll
        for (int r = 0; r < 4; ++r) {
          const unsigned k = (__float_as_uint(acc[i][j][r]) | 63u) ^ xo;
          const bool gt = k > K1[i][r];
          const unsigned t2 = K2[i][r] > k ? K2[i][r] : k;
          K2[i][r] = gt ? K1[i][r] : t2;
          K1[i][r] = gt ? k : K1[i][r];
        }
    }
  };

  // one K-tile, 2 pipelined phases; AC = current A frags, AN = next-kt A dest
  auto ktbody = [&](int kt, half8 (&AC)[4], half8 (&AN)[4]) {
    if ((kt & 15) == 0) {
#pragma unroll
      for (int i = 0; i < 4; ++i)
#pragma unroll
        for (int j = 0; j < 8; ++j) acc[i][j] = (f32x4){BIAS, BIAS, BIAS, BIAS};
    }
    const _Float16* Bb = &lds[kt & 3][1][0];
    // ---- phase A: issue B1 (this kt's j=4..7 operands), stage kt+3 ----
#pragma unroll
    for (int j = 0; j < 4; ++j) B1[j] = *(const half8*)&Bb[boff + (j + 4) * (16 * BK)];
    if (kt + 3 < G) { stageA(kt + 3); stageB(kt + 3); }
    __builtin_amdgcn_s_barrier();
    __builtin_amdgcn_s_setprio(1);
#pragma unroll
    for (int j = 0; j < 4; ++j)
#pragma unroll
      for (int i = 0; i < 4; ++i)
        acc[i][j] = __builtin_amdgcn_mfma_f32_16x16x32_f16(AC[i], B0[j], acc[i][j], 0, 0, 0);
    __builtin_amdgcn_s_setprio(0);
    __builtin_amdgcn_s_barrier();
    // ---- phase B: vm gate for buf kt+1, issue next-kt frags, MFMA j=4..7 ----
    if (kt < G - 3)       asm volatile("s_waitcnt vmcnt(8)" ::: "memory");
    else if (kt == G - 3) asm volatile("s_waitcnt vmcnt(4)" ::: "memory");
    else if (kt == G - 2) asm volatile("s_waitcnt vmcnt(0)" ::: "memory");
    if (kt + 1 < G) {
      const _Float16* An = &lds[(kt + 1) & 3][0][0];
      const _Float16* Bn = &lds[(kt + 1) & 3][1][0];
#pragma unroll
      for (int i = 0; i < 4; ++i) AN[i] = *(const half8*)&An[aoff + i * (16 * BK)];
#pragma unroll
      for (int j = 0; j < 4; ++j) B0[j] = *(const half8*)&Bn[boff + j * (16 * BK)];
    }
    __builtin_amdgcn_s_barrier();
    __builtin_amdgcn_s_setprio(1);
    if ((kt & 15) == 15) fold(0, 4, kt);  // final after phase A; interleaves under MFMA
#pragma unroll
    for (int j = 0; j < 4; ++j)
#pragma unroll
      for (int i = 0; i < 4; ++i)
        acc[i][j + 4] = __builtin_amdgcn_mfma_f32_16x16x32_f16(AC[i], B1[j], acc[i][j + 4], 0, 0, 0);
    __builtin_amdgcn_s_setprio(0);
    if ((kt & 15) == 15) fold(4, 8, kt);
    __builtin_amdgcn_s_barrier();
  };

  // prologue: stage K-tiles 0,1,2 (12 loads/wave); kt0 landed; pre-read kt0 frags
  stageA(0); stageB(0); stageA(1); stageB(1); stageA(2); stageB(2);
  asm volatile("s_waitcnt vmcnt(8)" ::: "memory");
  __builtin_amdgcn_s_barrier();
  {
    const _Float16* Ab = &lds[0][0][0];
    const _Float16* Bb = &lds[0][1][0];
#pragma unroll
    for (int i = 0; i < 4; ++i) A0[i] = *(const half8*)&Ab[aoff + i * (16 * BK)];
#pragma unroll
    for (int j = 0; j < 4; ++j) B0[j] = *(const half8*)&Bb[boff + j * (16 * BK)];
  }

#pragma unroll 1
  for (int kt2 = 0; kt2 < G; kt2 += 2) {
    ktbody(kt2, A0, A1);
    ktbody(kt2 + 1, A1, A0);
  }

  // butterfly-merge top-2 across the 16 column-lanes of each quad, recover
  // winner lane via ballot (first set bit = lowest l15 = lowest index on tie)
  const int nb = split * (K_CODES / NSPLIT);
#pragma unroll
  for (int i = 0; i < 4; ++i)
#pragma unroll
    for (int r = 0; r < 4; ++r) {
      const unsigned p1 = K1[i][r], p2 = K2[i][r];
      unsigned a1 = p1, a2 = p2;
#pragma unroll
      for (int d = 1; d < 16; d <<= 1) {
        const unsigned b1 = (unsigned)__shfl_xor((int)a1, d);
        const unsigned b2 = (unsigned)__shfl_xor((int)a2, d);
        const unsigned hi = a1 > b1 ? a1 : b1;
        const unsigned lo = a1 > b1 ? b1 : a1;
        const unsigned mx = a2 > b2 ? a2 : b2;
        a1 = hi;
        a2 = lo > mx ? lo : mx;
      }
      const unsigned long long bl1 = __ballot(p1 == a1);
      const int s1 = __ffsll((unsigned long long)((bl1 >> (quad * 16)) & 0xFFFFull)) - 1;
      const unsigned long long bl2 = __ballot((p2 == a2) || (p1 == a2 && l15 != s1));
      const int s2 = __ffsll((unsigned long long)((bl2 >> (quad * 16)) & 0xFFFFull)) - 1;
      if (l15 == 0) {
        const int code1 = 63 - (int)(a1 & 63u);
        const int code2 = 63 - (int)(a2 & 63u);
        const int col1 = nb + (code1 >> 3) * BN + wn * 128 + (code1 & 7) * 16 + s1;
        const int col2 = nb + (code2 >> 3) * BN + wn * 128 + (code2 & 7) * 16 + s2;
        const int rl = wm * 64 + i * 16 + quad * 4 + r;
        const size_t o = (size_t)(row0 + rl) * 64 + (size_t)(split * 4 + wn * 2);
        pv[o] = __uint_as_float(a1); pi[o] = col1;      // values stay +4-biased;
        pv[o + 1] = __uint_as_float(a2); pi[o + 1] = col2;  // margin test is relative
      }
    }
}

__global__ void recheck_gather(const float* __restrict__ pv, const int* __restrict__ pi,
                               const float* __restrict__ x, const float* __restrict__ cb,
                               float* __restrict__ out) {
  const int row = blockIdx.x;
  const int lane = threadIdx.x;   // 64 candidates = 16 splits x 2 classes x top-2
  float v = pv[(size_t)row * 64 + lane];
  int ci = pi[(size_t)row * 64 + lane];

  // wave max with lowest-index tie-break
  float m1 = v; int mi1 = ci;
#pragma unroll
  for (int d = 1; d < 64; d <<= 1) {
    float ov = __shfl_xor(m1, d);
    int oi = __shfl_xor(mi1, d);
    if (ov > m1 || (ov == m1 && oi < mi1)) { m1 = ov; mi1 = oi; }
  }

  const bool flag = (v >= m1 - MARGIN);
  const unsigned long long mask = __ballot(flag);
  int winner;
  if (__popcll(mask) == 1) {
    winner = mi1;   // approx winner is >=14-sigma clear of every other candidate
  } else {
    // exact fp64 dot from original fp32 inputs for each flagged candidate
    double e = -1.0e300;
    if (flag) {
      const float* xr = x + (size_t)row * DIM;
      const float* cr = cb + (size_t)ci * DIM;
      double s = 0.0;
#pragma unroll 4
      for (int t = 0; t < DIM; t += 4) {
        const float4 a = *(const float4*)(xr + t);
        const float4 b = *(const float4*)(cr + t);
        s += (double)a.x * b.x + (double)a.y * b.y + (double)a.z * b.z + (double)a.w * b.w;
      }
      e = s;
    }
    int ei = flag ? ci : 0x7fffffff;
#pragma unroll
    for (int d = 1; d < 64; d <<= 1) {
      double oe = __shfl_xor(e, d);
      int oi = __shfl_xor(ei, d);
      if (oe > e || (oe == e && oi < ei)) { e = oe; ei = oi; }
    }
    winner = ei;
  }

  const float4* src = (const float4*)(cb + (size_t)winner * DIM);
  float4* dst = (float4*)(out + (size_t)row * DIM);
  dst[lane] = src[lane];         // 512 f32 = 128 float4, 64 lanes x 2
  dst[lane + 64] = src[lane + 64];
}

extern "C" void kernel_launch(void* const* d_in, const int* in_sizes, int n_in,
                              void* d_out, int out_size, void* d_ws, size_t ws_size,
                              hipStream_t stream) {
  const float* x = (const float*)d_in[0];
  const float* cb = (const float*)d_in[1];
  float* out = (float*)d_out;

  // ws layout: x_f16(8MB) c_f16(16MB) pv(2MB) pi(2MB)
  _Float16* xh = (_Float16*)d_ws;
  _Float16* ch = xh + (size_t)M_ROWS * DIM;
  float* pv = (float*)(ch + (size_t)K_CODES * DIM);
  int* pi = (int*)(pv + (size_t)M_ROWS * NSPLIT * 2 * 2);

  const int n4 = (M_ROWS + K_CODES) * DIM / 4;
  to_f16_all<<<n4 / 256, 256, 0, stream>>>(x, cb, xh, ch);
  vq_argmax<<<dim3(M_ROWS / BM, NSPLIT), 512, 0, stream>>>(xh, ch, pv, pi);
  recheck_gather<<<M_ROWS, 64, 0, stream>>>(pv, pi, x, cb, out);
}

// Round 4
// 258.809 us; speedup vs baseline: 12.8516x; 12.8516x over previous
//
#include <hip/hip_runtime.h>
#include <stdint.h>

// VectorQuantization: out[n] = codebook[argmax_k dot(x[n], codebook[k])]
// (L2-normalize is a positive row-scalar -> argmax-invariant -> skipped)
//
// R7 = R6's pipelined phase schedule, implemented WITHOUT the lambda
// reference-array parameters that caused R6's scratch-spill catastrophe
// (VGPR 112->88, 15 GB/dispatch scratch traffic, MfmaUtil 1.7%). The K-tile
// body is a text macro so ACUR/ANXT are literal array names with
// compile-time indices -> everything stays in registers.
//
// Schedule per kt (buffer bk=kt&3), 2 phases of 16 MFMA, fragment reads one
// phase ahead into alternate register sets (A0/A1 per-kt, B0/B1 per-phase):
//   phase A: issue B1 <- bk.B[4..7] (4 ds_read); stage kt+3 (4 gll);
//            barrier; 16 MFMA j=0..3 (AC,B0); counted vmcnt; barrier.
//   phase B: issue ANXT <- (kt+1).A, B0 <- (kt+1).B[0..3] (8 ds_read);
//            barrier; [fold(0..3) @tile-end] 16 MFMA j=4..7 (AC,B1);
//            [fold(4..7)]; barrier.
// R6 race fixed: the counted vmcnt(8) now precedes the phase-A/B barrier,
// so when ANY wave reads buf kt+1, ALL waves have confirmed their kt+1
// stages retired (vmcnt is per-wave; the barrier globalizes it).
//
// Race ledger: stage of kt (issued phase A of kt, targets (kt+3)&3=(kt-1)&3)
// vs reads of buf kt-1: last reads are B[4..7], issued before barrier#1 of
// kt-1 and lgkm-complete before its phase-B MFMA -> >=2 barriers before the
// stage issue. vmcnt(8) at phase A of kt: outstanding = kt+3(4),kt+2(4),
// kt+1(4)=12 -> oldest 4 (kt+1) retired. Tail: vmcnt(4) @G-3, vmcnt(0) @G-2,
// no reads @G-1. Prologue: stage kt0,1,2 (12 loads), vmcnt(8) -> buf0
// landed, barrier, pre-read kt0 fragments.
//
// Carried: zero-bank-conflict XOR chunk swizzle (SQ_LDS_BANK_CONFLICT == 0),
// packed-key top-2 epilogue (+4.0 bias -> u32-monotone, 6-bit inverted
// (tile,j) code in low mantissa, <=64 ulp << MARGIN), ballot winner-lane
// recovery, exact-fp64 recheck within MARGIN, fused to_f16.

typedef _Float16 half8 __attribute__((ext_vector_type(8)));
typedef _Float16 half4v __attribute__((ext_vector_type(4)));
typedef float f32x4 __attribute__((ext_vector_type(4)));

#define M_ROWS 8192
#define DIM 512
#define K_CODES 16384
#define BM 256
#define BN 256
#define BK 32
#define NSPLIT 16
#define NT ((K_CODES / NSPLIT) / BN) /* 4 col-tiles per block */
#define KT_CT (DIM / BK)             /* 16 K-tiles per col-tile */
#define G (NT * KT_CT)               /* 64 K-tiles per block */
#define MARGIN 2.0e-3f
#define BIAS 4.0f

typedef __attribute__((address_space(1))) uint32_t as1_u32;
typedef __attribute__((address_space(3))) uint32_t as3_u32;

__device__ __forceinline__ void gll16(const void* g, void* l) {
  // async global->LDS, 16B/lane; LDS dest = wave-uniform base + lane*16
  __builtin_amdgcn_global_load_lds((const as1_u32*)(uintptr_t)g,
                                   (as3_u32*)(uintptr_t)l, 16, 0, 0);
}

__global__ void to_f16_all(const float* __restrict__ x, const float* __restrict__ cb,
                           _Float16* __restrict__ xh, _Float16* __restrict__ ch) {
  const int NX = M_ROWS * DIM / 4;
  int i = blockIdx.x * 256 + threadIdx.x;
  float4 v;
  if (i < NX) v = reinterpret_cast<const float4*>(x)[i];
  else        v = reinterpret_cast<const float4*>(cb)[i - NX];
  half4v h = {(_Float16)v.x, (_Float16)v.y, (_Float16)v.z, (_Float16)v.w};
  if (i < NX) reinterpret_cast<half4v*>(xh)[i] = h;
  else        reinterpret_cast<half4v*>(ch)[i - NX] = h;
}

__global__ __launch_bounds__(512, 2) void vq_argmax(
    const _Float16* __restrict__ xh, const _Float16* __restrict__ ch,
    float* __restrict__ pv, int* __restrict__ pi) {
  // 4 rotating single-K-tile buffers x {A,B} x (256 rows x 32 k) = 128 KiB
  __shared__ _Float16 lds[4][2][BM * BK];

  const int tid = threadIdx.x;
  const int lane = tid & 63;
  const int w = tid >> 6;
  const int wm = w >> 1, wn = w & 1;       // 4M x 2N wave grid
  const int l15 = lane & 15, quad = lane >> 4;
  const int row0 = blockIdx.x * BM;
  const int split = blockIdx.y;
  // swizzled k-chunk element offset for this lane's fragment reads
  const int kq = ((quad ^ ((l15 >> 1) & 3)) << 3);
  const int aoff = (wm * 64 + l15) * BK + kq;
  const int boff = (wn * 128 + l15) * BK + kq;

  // staging: slot s = r*512+tid holds logical chunk (row=s>>2, kc=(s&3)^((row>>1)&3))
  int eoff0, eoff1, doff0, doff1;
  {
    const int s1 = 512 + tid;
    const int r0 = tid >> 2, r1 = s1 >> 2;
    eoff0 = r0 * DIM + ((((tid & 3) ^ ((r0 >> 1) & 3))) << 3);
    eoff1 = r1 * DIM + ((((s1 & 3) ^ ((r1 >> 1) & 3))) << 3);
    doff0 = (tid & 448) << 3;
    doff1 = (512 + (tid & 448)) << 3;
  }
  const _Float16* Asrc = xh + (size_t)row0 * DIM;
  const _Float16* Bsrc = ch + (size_t)split * (K_CODES / NSPLIT) * DIM;

  auto stageA = [&](int t) {
    const int b = t & 3, ko = (t & 15) * BK;
    const _Float16* g = Asrc + ko;
    _Float16* l = &lds[b][0][0];
    gll16(g + eoff0, l + doff0);
    gll16(g + eoff1, l + doff1);
  };
  auto stageB = [&](int t) {
    const int b = t & 3, ko = (t & 15) * BK;
    const _Float16* g = Bsrc + (size_t)(t >> 4) * (BN * DIM) + ko;
    _Float16* l = &lds[b][1][0];
    gll16(g + eoff0, l + doff0);
    gll16(g + eoff1, l + doff1);
  };

  // packed top-2 keys per (i,r) row-slot: high bits = biased-sim f32 bits,
  // low 6 bits = inverted (coltile,j) code (bigger key = better / lower idx)
  unsigned K1[4][4], K2[4][4];
#pragma unroll
  for (int i = 0; i < 4; ++i)
#pragma unroll
    for (int r = 0; r < 4; ++r) { K1[i][r] = 0u; K2[i][r] = 0u; }

  f32x4 acc[4][8];
  half8 A0[4], A1[4], B0[4], B1[4];

  auto fold = [&](int j0, int j1, int kt) {
    const unsigned icb = 63u - (unsigned)(kt >> 4) * 8u;  // icode = icb - j
#pragma unroll
    for (int j = j0; j < j1; ++j) {
      const unsigned xo = 63u ^ (icb - (unsigned)j);
#pragma unroll
      for (int i = 0; i < 4; ++i)
#pragma unroll
        for (int r = 0; r < 4; ++r) {
          const unsigned k = (__float_as_uint(acc[i][j][r]) | 63u) ^ xo;
          const bool gt = k > K1[i][r];
          const unsigned t2 = K2[i][r] > k ? K2[i][r] : k;
          K2[i][r] = gt ? K1[i][r] : t2;
          K1[i][r] = gt ? k : K1[i][r];
        }
    }
  };

// one K-tile, 2 pipelined phases; ACUR/ANXT are literal array names (no
// reference binding -> no SROA failure -> no scratch).
#define KTBODY(KT, ACUR, ANXT)                                                \
  {                                                                           \
    const int kt_ = (KT);                                                     \
    if ((kt_ & 15) == 0) {                                                    \
      _Pragma("unroll") for (int i = 0; i < 4; ++i)                           \
        _Pragma("unroll") for (int j = 0; j < 8; ++j)                         \
          acc[i][j] = (f32x4){BIAS, BIAS, BIAS, BIAS};                        \
    }                                                                         \
    {                                                                         \
      const _Float16* Bb_ = &lds[kt_ & 3][1][0];                              \
      _Pragma("unroll") for (int j = 0; j < 4; ++j)                           \
        B1[j] = *(const half8*)&Bb_[boff + (j + 4) * (16 * BK)];              \
    }                                                                         \
    if (kt_ + 3 < G) { stageA(kt_ + 3); stageB(kt_ + 3); }                    \
    __builtin_amdgcn_s_barrier();                                             \
    __builtin_amdgcn_s_setprio(1);                                            \
    _Pragma("unroll") for (int j = 0; j < 4; ++j)                             \
      _Pragma("unroll") for (int i = 0; i < 4; ++i)                           \
        acc[i][j] = __builtin_amdgcn_mfma_f32_16x16x32_f16(                   \
            ACUR[i], B0[j], acc[i][j], 0, 0, 0);                              \
    __builtin_amdgcn_s_setprio(0);                                            \
    if (kt_ < G - 3)       asm volatile("s_waitcnt vmcnt(8)" ::: "memory");   \
    else if (kt_ == G - 3) asm volatile("s_waitcnt vmcnt(4)" ::: "memory");   \
    else if (kt_ == G - 2) asm volatile("s_waitcnt vmcnt(0)" ::: "memory");   \
    __builtin_amdgcn_s_barrier();                                             \
    if (kt_ + 1 < G) {                                                        \
      const _Float16* An_ = &lds[(kt_ + 1) & 3][0][0];                        \
      const _Float16* Bn_ = &lds[(kt_ + 1) & 3][1][0];                        \
      _Pragma("unroll") for (int i = 0; i < 4; ++i)                           \
        ANXT[i] = *(const half8*)&An_[aoff + i * (16 * BK)];                  \
      _Pragma("unroll") for (int j = 0; j < 4; ++j)                           \
        B0[j] = *(const half8*)&Bn_[boff + j * (16 * BK)];                    \
    }                                                                         \
    __builtin_amdgcn_s_barrier();                                             \
    __builtin_amdgcn_s_setprio(1);                                            \
    if ((kt_ & 15) == 15) fold(0, 4, kt_);                                    \
    _Pragma("unroll") for (int j = 0; j < 4; ++j)                             \
      _Pragma("unroll") for (int i = 0; i < 4; ++i)                           \
        acc[i][j + 4] = __builtin_amdgcn_mfma_f32_16x16x32_f16(               \
            ACUR[i], B1[j], acc[i][j + 4], 0, 0, 0);                          \
    __builtin_amdgcn_s_setprio(0);                                            \
    if ((kt_ & 15) == 15) fold(4, 8, kt_);                                    \
    __builtin_amdgcn_s_barrier();                                             \
  }

  // prologue: stage K-tiles 0,1,2 (12 loads/wave); buf0 landed; pre-read kt0
  stageA(0); stageB(0); stageA(1); stageB(1); stageA(2); stageB(2);
  asm volatile("s_waitcnt vmcnt(8)" ::: "memory");
  __builtin_amdgcn_s_barrier();
  {
    const _Float16* Ab = &lds[0][0][0];
    const _Float16* Bb = &lds[0][1][0];
#pragma unroll
    for (int i = 0; i < 4; ++i) A0[i] = *(const half8*)&Ab[aoff + i * (16 * BK)];
#pragma unroll
    for (int j = 0; j < 4; ++j) B0[j] = *(const half8*)&Bb[boff + j * (16 * BK)];
  }

#pragma unroll 1
  for (int kt2 = 0; kt2 < G; kt2 += 2) {
    KTBODY(kt2, A0, A1);
    KTBODY(kt2 + 1, A1, A0);
  }
#undef KTBODY

  // butterfly-merge top-2 across the 16 column-lanes of each quad, recover
  // winner lane via ballot (first set bit = lowest l15 = lowest index on tie)
  const int nb = split * (K_CODES / NSPLIT);
#pragma unroll
  for (int i = 0; i < 4; ++i)
#pragma unroll
    for (int r = 0; r < 4; ++r) {
      const unsigned p1 = K1[i][r], p2 = K2[i][r];
      unsigned a1 = p1, a2 = p2;
#pragma unroll
      for (int d = 1; d < 16; d <<= 1) {
        const unsigned b1 = (unsigned)__shfl_xor((int)a1, d);
        const unsigned b2 = (unsigned)__shfl_xor((int)a2, d);
        const unsigned hi = a1 > b1 ? a1 : b1;
        const unsigned lo = a1 > b1 ? b1 : a1;
        const unsigned mx = a2 > b2 ? a2 : b2;
        a1 = hi;
        a2 = lo > mx ? lo : mx;
      }
      const unsigned long long bl1 = __ballot(p1 == a1);
      const int s1 = __ffsll((unsigned long long)((bl1 >> (quad * 16)) & 0xFFFFull)) - 1;
      const unsigned long long bl2 = __ballot((p2 == a2) || (p1 == a2 && l15 != s1));
      const int s2 = __ffsll((unsigned long long)((bl2 >> (quad * 16)) & 0xFFFFull)) - 1;
      if (l15 == 0) {
        const int code1 = 63 - (int)(a1 & 63u);
        const int code2 = 63 - (int)(a2 & 63u);
        const int col1 = nb + (code1 >> 3) * BN + wn * 128 + (code1 & 7) * 16 + s1;
        const int col2 = nb + (code2 >> 3) * BN + wn * 128 + (code2 & 7) * 16 + s2;
        const int rl = wm * 64 + i * 16 + quad * 4 + r;
        const size_t o = (size_t)(row0 + rl) * 64 + (size_t)(split * 4 + wn * 2);
        pv[o] = __uint_as_float(a1); pi[o] = col1;      // values stay +4-biased;
        pv[o + 1] = __uint_as_float(a2); pi[o + 1] = col2;  // margin test is relative
      }
    }
}

__global__ void recheck_gather(const float* __restrict__ pv, const int* __restrict__ pi,
                               const float* __restrict__ x, const float* __restrict__ cb,
                               float* __restrict__ out) {
  const int row = blockIdx.x;
  const int lane = threadIdx.x;   // 64 candidates = 16 splits x 2 classes x top-2
  float v = pv[(size_t)row * 64 + lane];
  int ci = pi[(size_t)row * 64 + lane];

  // wave max with lowest-index tie-break
  float m1 = v; int mi1 = ci;
#pragma unroll
  for (int d = 1; d < 64; d <<= 1) {
    float ov = __shfl_xor(m1, d);
    int oi = __shfl_xor(mi1, d);
    if (ov > m1 || (ov == m1 && oi < mi1)) { m1 = ov; mi1 = oi; }
  }

  const bool flag = (v >= m1 - MARGIN);
  const unsigned long long mask = __ballot(flag);
  int winner;
  if (__popcll(mask) == 1) {
    winner = mi1;   // approx winner is >=14-sigma clear of every other candidate
  } else {
    // exact fp64 dot from original fp32 inputs for each flagged candidate
    double e = -1.0e300;
    if (flag) {
      const float* xr = x + (size_t)row * DIM;
      const float* cr = cb + (size_t)ci * DIM;
      double s = 0.0;
#pragma unroll 4
      for (int t = 0; t < DIM; t += 4) {
        const float4 a = *(const float4*)(xr + t);
        const float4 b = *(const float4*)(cr + t);
        s += (double)a.x * b.x + (double)a.y * b.y + (double)a.z * b.z + (double)a.w * b.w;
      }
      e = s;
    }
    int ei = flag ? ci : 0x7fffffff;
#pragma unroll
    for (int d = 1; d < 64; d <<= 1) {
      double oe = __shfl_xor(e, d);
      int oi = __shfl_xor(ei, d);
      if (oe > e || (oe == e && oi < ei)) { e = oe; ei = oi; }
    }
    winner = ei;
  }

  const float4* src = (const float4*)(cb + (size_t)winner * DIM);
  float4* dst = (float4*)(out + (size_t)row * DIM);
  dst[lane] = src[lane];         // 512 f32 = 128 float4, 64 lanes x 2
  dst[lane + 64] = src[lane + 64];
}

extern "C" void kernel_launch(void* const* d_in, const int* in_sizes, int n_in,
                              void* d_out, int out_size, void* d_ws, size_t ws_size,
                              hipStream_t stream) {
  const float* x = (const float*)d_in[0];
  const float* cb = (const float*)d_in[1];
  float* out = (float*)d_out;

  // ws layout: x_f16(8MB) c_f16(16MB) pv(2MB) pi(2MB)
  _Float16* xh = (_Float16*)d_ws;
  _Float16* ch = xh + (size_t)M_ROWS * DIM;
  float* pv = (float*)(ch + (size_t)K_CODES * DIM);
  int* pi = (int*)(pv + (size_t)M_ROWS * NSPLIT * 2 * 2);

  const int n4 = (M_ROWS + K_CODES) * DIM / 4;
  to_f16_all<<<n4 / 256, 256, 0, stream>>>(x, cb, xh, ch);
  vq_argmax<<<dim3(M_ROWS / BM, NSPLIT), 512, 0, stream>>>(xh, ch, pv, pi);
  recheck_gather<<<M_ROWS, 64, 0, stream>>>(pv, pi, x, cb, out);
}

// Round 5
// 230.456 us; speedup vs baseline: 14.4327x; 1.1230x over previous
//
#include <hip/hip_runtime.h>
#include <stdint.h>

// VectorQuantization: out[n] = codebook[argmax_k dot(x[n], codebook[k])]
// (argmax invariant to positive per-row scaling -> L2-normalize skipped,
//  and per-row max-norm int8 quantization is equally argmax-preserving)
//
// R8: int8 MFMA path. x rows quantized by per-row absmax (127/max|x_i|),
// codebook by ONE global absmax (per-row codebook scales would change the
// ranking; a single positive scale does not). Integer dot noise sigma ~276
// int units ~1.2e-4 in sim units == the fp16 path's measured 1.3e-4, so the
// established top-2-per-split + margin + exact-fp64 recheck keeps the same
// correctness envelope (MARGIN_I = 8000 ints ~ 29 sigma).
// mfma_i32_16x16x64_i8 = 2x MACs/byte and 2x rate vs f16 -> MFMA work,
// LDS traffic, and staged bytes all halve.
//
// Structure = R5's best-measured schedule, byte-identical machinery:
// a BK=64-element i8 row is 64 B = the same 4x16B-chunk row geometry as the
// f16 BK=32 tile, so the zero-bank-conflict XOR chunk swizzle, gll16
// staging, 4-buffer lookahead-3 vmcnt(8) ledger carry over unchanged.
// G=32 K-tiles (8 per col-tile x 4 col-tiles), 12 ds_read_b128 + 32 MFMA
// per K-tile per wave, single end-of-tile barrier.
//
// Race ledger (unchanged from R5): during kt only buffer kt&3 is read;
// stages issued during kt target (kt+3)&3==(kt-1)&3 whose last reads were
// pre-barrier of kt-1. vmcnt(8) at end of kt: outstanding = stages for
// kt+1,kt+2,kt+3 (12) -> oldest 4 (kt+1) retired before next iteration's
// reads; barrier globalizes. Tail 4 -> 0 at G-3/G-2.
//
// Fold: int keys, key = (D<<5)|icode_inv (monotone in D, gap 32 > code range,
// inverted 5-bit (coltile,j) code = lowest-index tie-break for free).
// Epilogue butterfly/ballot identical, signed compares. pv stores (float)D.

typedef int i32x4 __attribute__((ext_vector_type(4)));

#define M_ROWS 8192
#define DIM 512
#define DIMB 512                      /* bytes per i8 row */
#define K_CODES 16384
#define BM 256
#define BN 256
#define BKB 64                        /* K-tile depth in elements == bytes */
#define NSPLIT 16
#define NT ((K_CODES / NSPLIT) / BN)  /* 4 col-tiles per block */
#define KT_CT (DIM / BKB)             /* 8 K-tiles per col-tile */
#define G (NT * KT_CT)                /* 32 K-tiles per block */
#define MARGIN_I 8000.0f
#define INT_MIN_K (-2147483647 - 1)

typedef __attribute__((address_space(1))) uint32_t as1_u32;
typedef __attribute__((address_space(3))) uint32_t as3_u32;

__device__ __forceinline__ void gll16(const void* g, void* l) {
  // async global->LDS, 16B/lane; LDS dest = wave-uniform base + lane*16
  __builtin_amdgcn_global_load_lds((const as1_u32*)(uintptr_t)g,
                                   (as3_u32*)(uintptr_t)l, 16, 0, 0);
}

__device__ __forceinline__ float absmax4(float4 v) {
  return fmaxf(fmaxf(fabsf(v.x), fabsf(v.y)), fmaxf(fabsf(v.z), fabsf(v.w)));
}

__device__ __forceinline__ unsigned pack4(float a, float b, float c, float d, float inv) {
  const int q0 = __float2int_rn(a * inv), q1 = __float2int_rn(b * inv);
  const int q2 = __float2int_rn(c * inv), q3 = __float2int_rn(d * inv);
  return (unsigned)(q0 & 255) | ((unsigned)(q1 & 255) << 8) |
         ((unsigned)(q2 & 255) << 16) | ((unsigned)(q3 & 255) << 24);
}

// one wave per row: per-row absmax -> quantize 512 f32 -> 512 i8
__global__ void x_quant(const float* __restrict__ x, signed char* __restrict__ xq,
                        unsigned* __restrict__ cbmax) {
  const int wv = threadIdx.x >> 6, lane = threadIdx.x & 63;
  const int row = blockIdx.x * 8 + wv;
  const float* xr = x + (size_t)row * DIM + lane * 8;
  const float4 v0 = *(const float4*)xr;
  const float4 v1 = *(const float4*)(xr + 4);
  float m = fmaxf(absmax4(v0), absmax4(v1));
#pragma unroll
  for (int d = 1; d < 64; d <<= 1) m = fmaxf(m, __shfl_xor(m, d));
  const float inv = m > 0.f ? 127.0f / m : 0.f;
  uint2 u;
  u.x = pack4(v0.x, v0.y, v0.z, v0.w, inv);
  u.y = pack4(v1.x, v1.y, v1.z, v1.w, inv);
  ((uint2*)(xq + (size_t)row * DIMB))[lane] = u;
  if (blockIdx.x == 0 && threadIdx.x == 0) *cbmax = 0u;  // init for cb_absmax
}

__global__ void cb_absmax(const float* __restrict__ cb, unsigned* __restrict__ cbmax) {
  __shared__ float sm[4];
  const int n4 = K_CODES * DIM / 4;
  float m = 0.f;
  for (int i = blockIdx.x * 256 + threadIdx.x; i < n4; i += 256 * 1024)
    m = fmaxf(m, absmax4(((const float4*)cb)[i]));
#pragma unroll
  for (int d = 1; d < 64; d <<= 1) m = fmaxf(m, __shfl_xor(m, d));
  if ((threadIdx.x & 63) == 0) sm[threadIdx.x >> 6] = m;
  __syncthreads();
  if (threadIdx.x == 0) {
    m = fmaxf(fmaxf(sm[0], sm[1]), fmaxf(sm[2], sm[3]));
    atomicMax((int*)cbmax, __float_as_int(m));  // positive floats: bit-monotone
  }
}

__global__ void cb_quant(const float* __restrict__ cb, signed char* __restrict__ cq,
                         const unsigned* __restrict__ cbmax) {
  const float mx = __int_as_float((int)*cbmax);
  const float inv = mx > 0.f ? 127.0f / mx : 0.f;
  const size_t t = (size_t)blockIdx.x * 256 + threadIdx.x;  // 8 elems/thread
  const float* src = cb + t * 8;
  const float4 v0 = *(const float4*)src;
  const float4 v1 = *(const float4*)(src + 4);
  uint2 u;
  u.x = pack4(v0.x, v0.y, v0.z, v0.w, inv);
  u.y = pack4(v1.x, v1.y, v1.z, v1.w, inv);
  ((uint2*)cq)[t] = u;
}

__global__ __launch_bounds__(512, 2) void vq_argmax(
    const signed char* __restrict__ xq, const signed char* __restrict__ cq,
    float* __restrict__ pv, int* __restrict__ pi) {
  // 4 rotating single-K-tile buffers x {A,B} x (256 rows x 64B) = 128 KiB
  __shared__ signed char lds[4][2][BM * BKB];

  const int tid = threadIdx.x;
  const int lane = tid & 63;
  const int w = tid >> 6;
  const int wm = w >> 1, wn = w & 1;       // 4M x 2N wave grid
  const int l15 = lane & 15, quad = lane >> 4;
  const int row0 = blockIdx.x * BM;
  const int split = blockIdx.y;
  // swizzled 16B-chunk byte offset for this lane's fragment reads
  const int kq = ((quad ^ ((l15 >> 1) & 3)) << 4);
  const int aoff = (wm * 64 + l15) * BKB + kq;
  const int boff = (wn * 128 + l15) * BKB + kq;

  // staging: slot s = r*512+tid holds logical chunk (row=s>>2, kc=(s&3)^((row>>1)&3))
  int eoff0, eoff1, doff0, doff1;
  {
    const int s1 = 512 + tid;
    const int r0 = tid >> 2, r1 = s1 >> 2;
    eoff0 = r0 * DIMB + (((tid & 3) ^ ((r0 >> 1) & 3)) << 4);
    eoff1 = r1 * DIMB + (((s1 & 3) ^ ((r1 >> 1) & 3)) << 4);
    doff0 = (tid & 448) << 4;
    doff1 = (512 + (tid & 448)) << 4;
  }
  const signed char* Asrc = xq + (size_t)row0 * DIMB;
  const signed char* Bsrc = cq + (size_t)split * (K_CODES / NSPLIT) * DIMB;

  auto stageA = [&](int t) {
    const signed char* g = Asrc + (t & 7) * BKB;
    signed char* l = &lds[t & 3][0][0];
    gll16(g + eoff0, l + doff0);
    gll16(g + eoff1, l + doff1);
  };
  auto stageB = [&](int t) {
    const signed char* g = Bsrc + (size_t)(t >> 3) * (BN * DIMB) + (t & 7) * BKB;
    signed char* l = &lds[t & 3][1][0];
    gll16(g + eoff0, l + doff0);
    gll16(g + eoff1, l + doff1);
  };

  // packed top-2 int keys per (i,r) row-slot: key = (D<<5) | icode_inv
  int K1[4][4], K2[4][4];
#pragma unroll
  for (int i = 0; i < 4; ++i)
#pragma unroll
    for (int r = 0; r < 4; ++r) { K1[i][r] = INT_MIN_K; K2[i][r] = INT_MIN_K; }

  i32x4 acc[4][8];

  auto fold = [&](int j0, int j1, int kt) {
    const int icb = 31 - (kt >> 3) * 8;   // icode_inv = icb - j
#pragma unroll
    for (int j = j0; j < j1; ++j) {
      const int xo = icb - j;
#pragma unroll
      for (int i = 0; i < 4; ++i)
#pragma unroll
        for (int r = 0; r < 4; ++r) {
          const int k = (int)(((unsigned)acc[i][j][r] << 5) | (unsigned)xo);
          const bool gt = k > K1[i][r];
          const int t2 = K2[i][r] > k ? K2[i][r] : k;
          K2[i][r] = gt ? K1[i][r] : t2;
          K1[i][r] = gt ? k : K1[i][r];
        }
    }
  };

  // prologue: stage K-tiles 0,1,2 (12 loads/wave); buf0 landed; sync
  stageA(0); stageB(0); stageA(1); stageB(1); stageA(2); stageB(2);
  asm volatile("s_waitcnt vmcnt(8)" ::: "memory");
  __builtin_amdgcn_s_barrier();
  asm volatile("" ::: "memory");

#pragma unroll 1
  for (int kt = 0; kt < G; ++kt) {
    const int bk = kt & 3;
    if ((kt & 7) == 0) {
#pragma unroll
      for (int i = 0; i < 4; ++i)
#pragma unroll
        for (int j = 0; j < 8; ++j) acc[i][j] = (i32x4){0, 0, 0, 0};
    }
    const signed char* Ab = &lds[bk][0][0];
    const signed char* Bb = &lds[bk][1][0];

    // all 12 fragment reads up front in need-order; counted lgkm lets the
    // later B reads complete under the first MFMA group
    i32x4 A_[4], B_[8];
#pragma unroll
    for (int i = 0; i < 4; ++i) A_[i] = *(const i32x4*)&Ab[aoff + i * (16 * BKB)];
#pragma unroll
    for (int j = 0; j < 8; ++j) B_[j] = *(const i32x4*)&Bb[boff + j * (16 * BKB)];

    if (kt + 3 < G) { stageA(kt + 3); stageB(kt + 3); }

    __builtin_amdgcn_s_setprio(1);
#pragma unroll
    for (int j = 0; j < 4; ++j)
#pragma unroll
      for (int i = 0; i < 4; ++i)
        acc[i][j] = __builtin_amdgcn_mfma_i32_16x16x64_i8(A_[i], B_[j], acc[i][j], 0, 0, 0);
    __builtin_amdgcn_s_setprio(0);
    if ((kt & 7) == 7) fold(0, 4, kt);   // VALU half-fold under next MFMA group
    __builtin_amdgcn_s_setprio(1);
#pragma unroll
    for (int j = 4; j < 8; ++j)
#pragma unroll
      for (int i = 0; i < 4; ++i)
        acc[i][j] = __builtin_amdgcn_mfma_i32_16x16x64_i8(A_[i], B_[j], acc[i][j], 0, 0, 0);
    __builtin_amdgcn_s_setprio(0);
    if ((kt & 7) == 7) fold(4, 8, kt);

    // steady state: stages for kt+1..kt+3 outstanding (12); wait to 8 so
    // kt+1's buffer is landed. Tail drains 4 -> 0.
    if (kt < G - 3)       asm volatile("s_waitcnt vmcnt(8)" ::: "memory");
    else if (kt == G - 3) asm volatile("s_waitcnt vmcnt(4)" ::: "memory");
    else if (kt == G - 2) asm volatile("s_waitcnt vmcnt(0)" ::: "memory");
    __builtin_amdgcn_s_barrier();
    asm volatile("" ::: "memory");
  }

  // butterfly-merge top-2 across the 16 column-lanes of each quad, recover
  // winner lane via ballot (first set bit = lowest l15 = lowest index on tie)
  const int nb = split * (K_CODES / NSPLIT);
#pragma unroll
  for (int i = 0; i < 4; ++i)
#pragma unroll
    for (int r = 0; r < 4; ++r) {
      const int p1 = K1[i][r], p2 = K2[i][r];
      int a1 = p1, a2 = p2;
#pragma unroll
      for (int d = 1; d < 16; d <<= 1) {
        const int b1 = __shfl_xor(a1, d);
        const int b2 = __shfl_xor(a2, d);
        const int hi = a1 > b1 ? a1 : b1;
        const int lo = a1 > b1 ? b1 : a1;
        const int mx = a2 > b2 ? a2 : b2;
        a1 = hi;
        a2 = lo > mx ? lo : mx;
      }
      const unsigned long long bl1 = __ballot(p1 == a1);
      const int s1 = __ffsll((unsigned long long)((bl1 >> (quad * 16)) & 0xFFFFull)) - 1;
      const unsigned long long bl2 = __ballot((p2 == a2) || (p1 == a2 && l15 != s1));
      const int s2 = __ffsll((unsigned long long)((bl2 >> (quad * 16)) & 0xFFFFull)) - 1;
      if (l15 == 0) {
        const int code1 = 31 - (a1 & 31);
        const int code2 = 31 - (a2 & 31);
        const int col1 = nb + (code1 >> 3) * BN + wn * 128 + (code1 & 7) * 16 + s1;
        const int col2 = nb + (code2 >> 3) * BN + wn * 128 + (code2 & 7) * 16 + s2;
        const int rl = wm * 64 + i * 16 + quad * 4 + r;
        const size_t o = (size_t)(row0 + rl) * 64 + (size_t)(split * 4 + wn * 2);
        pv[o] = (float)(a1 >> 5); pi[o] = col1;       // D in int units; margin
        pv[o + 1] = (float)(a2 >> 5); pi[o + 1] = col2;  // test is relative/row
      }
    }
}

__global__ void recheck_gather(const float* __restrict__ pv, const int* __restrict__ pi,
                               const float* __restrict__ x, const float* __restrict__ cb,
                               float* __restrict__ out) {
  const int row = blockIdx.x;
  const int lane = threadIdx.x;   // 64 candidates = 16 splits x 2 halves x top-2
  float v = pv[(size_t)row * 64 + lane];
  int ci = pi[(size_t)row * 64 + lane];

  // wave max with lowest-index tie-break
  float m1 = v; int mi1 = ci;
#pragma unroll
  for (int d = 1; d < 64; d <<= 1) {
    float ov = __shfl_xor(m1, d);
    int oi = __shfl_xor(mi1, d);
    if (ov > m1 || (ov == m1 && oi < mi1)) { m1 = ov; mi1 = oi; }
  }

  const bool flag = (v >= m1 - MARGIN_I);
  const unsigned long long mask = __ballot(flag);
  int winner;
  if (__popcll(mask) == 1) {
    winner = mi1;   // approx winner is ~29-sigma clear of every other candidate
  } else {
    // exact fp64 dot from original fp32 inputs for each flagged candidate
    double e = -1.0e300;
    if (flag) {
      const float* xr = x + (size_t)row * DIM;
      const float* cr = cb + (size_t)ci * DIM;
      double s = 0.0;
#pragma unroll 4
      for (int t = 0; t < DIM; t += 4) {
        const float4 a = *(const float4*)(xr + t);
        const float4 b = *(const float4*)(cr + t);
        s += (double)a.x * b.x + (double)a.y * b.y + (double)a.z * b.z + (double)a.w * b.w;
      }
      e = s;
    }
    int ei = flag ? ci : 0x7fffffff;
#pragma unroll
    for (int d = 1; d < 64; d <<= 1) {
      double oe = __shfl_xor(e, d);
      int oi = __shfl_xor(ei, d);
      if (oe > e || (oe == e && oi < ei)) { e = oe; ei = oi; }
    }
    winner = ei;
  }

  const float4* src = (const float4*)(cb + (size_t)winner * DIM);
  float4* dst = (float4*)(out + (size_t)row * DIM);
  dst[lane] = src[lane];         // 512 f32 = 128 float4, 64 lanes x 2
  dst[lane + 64] = src[lane + 64];
}

extern "C" void kernel_launch(void* const* d_in, const int* in_sizes, int n_in,
                              void* d_out, int out_size, void* d_ws, size_t ws_size,
                              hipStream_t stream) {
  const float* x = (const float*)d_in[0];
  const float* cb = (const float*)d_in[1];
  float* out = (float*)d_out;

  // ws layout: xq(4MB) cq(8MB) pv(2MB) pi(2MB) cbmax(4B)
  signed char* xq = (signed char*)d_ws;
  signed char* cq = xq + (size_t)M_ROWS * DIMB;
  float* pv = (float*)(cq + (size_t)K_CODES * DIMB);
  int* pi = (int*)(pv + (size_t)M_ROWS * 64);
  unsigned* cbmax = (unsigned*)(pi + (size_t)M_ROWS * 64);

  x_quant<<<M_ROWS / 8, 512, 0, stream>>>(x, xq, cbmax);
  cb_absmax<<<1024, 256, 0, stream>>>(cb, cbmax);
  cb_quant<<<K_CODES * DIM / 8 / 256, 256, 0, stream>>>(cb, cq, cbmax);
  vq_argmax<<<dim3(M_ROWS / BM, NSPLIT), 512, 0, stream>>>(xq, cq, pv, pi);
  recheck_gather<<<M_ROWS, 64, 0, stream>>>(pv, pi, x, cb, out);
}